// Round 5
// baseline (12061.533 us; speedup 1.0000x reference)
//
#include <hip/hip_runtime.h>

// CRF forward algorithm on MI355X — round 5 (round 4 + type fixes).
// v_t = diag(2^feat) * (E @ v_{t-1}) in the linear domain, E = exp(trans).
//   * E as f16 in LDS (16 rows x 4096 x 2B = 128KB/block, dynamic LDS),
//     matvec via v_dot2_f32_f16 — no register-allocation dependence.
//   * inter-block sync: one flag word per (slot, block), store-only;
//     only wave 0 polls (256 words), other waves wait at the barrier.
//   * p staged to LDS as f16 AFTER normalizing by 1/pmax (no f16 overflow);
//     identical Racc/log2 bookkeeping as the absmax==0 rounds 1-3.
// Fix vs round 4: h2 must be __fp16-based (cvt_pkrtz/fdot2 return/take V2h);
// attribute set unconditionally (no static guards).

#define T_STEPS 1024
#define NRULES  4095
#define NTAGS   4096
#define RING    8
#define L2E     1.4426950408889634f
#define LN2     0.69314718055994530942

typedef __fp16 h2 __attribute__((ext_vector_type(2)));

#if __has_builtin(__builtin_amdgcn_fdot2)
#define FDOT2(a, b, c) __builtin_amdgcn_fdot2((a), (b), (c), false)
#else
__device__ __forceinline__ float FDOT2(h2 a, h2 b, float c) {
  return c + (float)a[0] * (float)b[0] + (float)a[1] * (float)b[1];
}
#endif

__device__ __forceinline__ float ld_agent(const float* p) {
  return __hip_atomic_load(p, __ATOMIC_RELAXED, __HIP_MEMORY_SCOPE_AGENT);
}
__device__ __forceinline__ void st_agent(float* p, float v) {
  __hip_atomic_store(p, v, __ATOMIC_RELAXED, __HIP_MEMORY_SCOPE_AGENT);
}

// ws layout: pring (8*4096 f32) | flags (8*256 u32) | lp (1 f32)
#define FLAGS_OFF (RING * NTAGS)           // in floats
#define LP_OFF    (FLAGS_OFF + RING * 256) // in floats

// Init: pring slot 0 = p_0 = [1,0,...]; flags slot 0 = 1, slots 1..7 = 0.
__global__ void crf_init(float* __restrict__ ws) {
  unsigned* flags = (unsigned*)(ws + FLAGS_OFF);
  int idx = blockIdx.x * blockDim.x + threadIdx.x;
  int stride = gridDim.x * blockDim.x;
  for (int i = idx; i < NTAGS; i += stride)
    ws[i] = (i == 0) ? 1.0f : 0.0f;                 // pring slot 0
  for (int i = idx; i < RING * 256; i += stride)
    flags[i] = (i < 256) ? 1u : 0u;
}

// Supervised path score (unchanged from the absmax==0 version).
__global__ void crf_logprob(const float* __restrict__ feats,
                            const float* __restrict__ trans,
                            const int* __restrict__ tags,
                            float* __restrict__ lp) {
  int t = threadIdx.x;
  int prev = (t == 0) ? 0 : tags[t - 1];
  int nxt  = tags[t];
  int er = prev - 1; if (er < 0) er += NRULES;
  float v = feats[(size_t)t * NRULES + er] + trans[(size_t)nxt * NTAGS + prev];
  #pragma unroll
  for (int d = 32; d; d >>= 1) v += __shfl_xor(v, d, 64);
  __shared__ float sb[16];
  if ((t & 63) == 0) sb[t >> 6] = v;
  __syncthreads();
  if (t == 0) {
    float s = 0.f;
    #pragma unroll
    for (int i = 0; i < 16; ++i) s += sb[i];
    lp[0] = s;
  }
}

// Persistent scan. Grid 256 x block 512 (8 waves), 1 block/CU (LDS-bound).
// Wave w owns rows {2w, 2w+1} of its block's 16 tags; lane l covers
// 16B chunks at offset 1024k + 16l, k=0..7 of the 4096-wide dot.
__launch_bounds__(512, 2)
__global__ void crf_scan(const float* __restrict__ feats,
                         const float* __restrict__ trans,
                         float* __restrict__ ws,
                         float* __restrict__ out)
{
  extern __shared__ __align__(16) char dynsm[];   // [0,131072): E f16; [131072,139264): p f16
  char* const PS = dynsm + 131072;

  float* const pring    = ws;
  unsigned* const flags = (unsigned*)(ws + FLAGS_OFF);
  const float* const lp = ws + LP_OFF;

  const int g    = blockIdx.x;
  const int tid  = threadIdx.x;
  const int wave = tid >> 6;
  const int lane = tid & 63;
  const int tagbase = g * 16 + 2 * wave;

  __shared__ float wmaxA[8];
  __shared__ int giveup;
  if (tid == 0) giveup = 0;

  // ---- one-time: E[r][c] = (f16) exp(trans[g*16+r][c]) into LDS ----
  // trans row 0 is all -1e4 -> exp2 underflows to +0 -> p[0] stays 0. [exact]
  {
    const size_t base = (size_t)(g * 16) * NTAGS;
    for (int i = tid; i < 16 * 2048; i += 512) {
      const int row = i >> 11, pr = i & 2047;
      const float2 v = *reinterpret_cast<const float2*>(
          trans + base + (size_t)row * NTAGS + 2 * pr);
      h2 e = __builtin_amdgcn_cvt_pkrtz(__builtin_amdgcn_exp2f(v.x * L2E),
                                        __builtin_amdgcn_exp2f(v.y * L2E));
      *reinterpret_cast<h2*>(dynsm + row * 8192 + 4 * pr) = e;
    }
  }
  __syncthreads();

  double Racc = 0.0;  // sum of log2(per-step max); identical on all threads

  for (int t = 1; t <= T_STEPS; ++t) {
    const int sprev = (t - 1) & (RING - 1);
    const int scur  = t & (RING - 1);
    const float* pprev = pring + sprev * NTAGS;

    // ---- wave 0 polls the 256 per-block flags of slot t-1; others wait ----
    if (wave == 0) {
      unsigned* fl = flags + sprev * 256;
      int rounds = 0;
      for (;;) {
        unsigned f0 = __hip_atomic_load(fl + lane,       __ATOMIC_RELAXED, __HIP_MEMORY_SCOPE_AGENT);
        unsigned f1 = __hip_atomic_load(fl + lane + 64,  __ATOMIC_RELAXED, __HIP_MEMORY_SCOPE_AGENT);
        unsigned f2 = __hip_atomic_load(fl + lane + 128, __ATOMIC_RELAXED, __HIP_MEMORY_SCOPE_AGENT);
        unsigned f3 = __hip_atomic_load(fl + lane + 192, __ATOMIC_RELAXED, __HIP_MEMORY_SCOPE_AGENT);
        bool ok = f0 && f1 && f2 && f3;
        if (__ballot(!ok) == 0ull) break;
        if (++rounds > (1 << 17)) { if (lane == 0) giveup = 1; break; }  // fail loud
        __builtin_amdgcn_s_sleep(1);
      }
      (void)__hip_atomic_load(fl, __ATOMIC_ACQUIRE, __HIP_MEMORY_SCOPE_AGENT);
    }
    __syncthreads();                       // barrier A (doubles as acquire chain)
    if (giveup) break;

    // ---- clear my flag for slot t-2 (all readers provably past it) ----
    if (t >= 2 && tid == 1)
      __hip_atomic_store(&flags[((t - 2) & (RING - 1)) * 256 + g], 0u,
                         __ATOMIC_RELAXED, __HIP_MEMORY_SCOPE_AGENT);

    // ---- load p_{t-1} (contiguous 8 floats/thread), block max ----
    float pv[8];
    #pragma unroll
    for (int i = 0; i < 8; ++i) pv[i] = ld_agent(&pprev[8 * tid + i]);
    float mloc = 0.0f;
    #pragma unroll
    for (int i = 0; i < 8; ++i) mloc = fmaxf(mloc, pv[i]);
    #pragma unroll
    for (int d = 32; d; d >>= 1) mloc = fmaxf(mloc, __shfl_xor(mloc, d, 64));
    if (lane == 0) wmaxA[wave] = mloc;

    // feats for my 2 rows
    const int fi0 = (tagbase == 0) ? 0 : tagbase - 1;
    const float fe0 = feats[(size_t)(t - 1) * NRULES + fi0] * L2E;
    const float fe1 = feats[(size_t)(t - 1) * NRULES + tagbase] * L2E;

    __syncthreads();                       // barrier B: wmax ready

    float pmax = wmaxA[0];
    #pragma unroll
    for (int i = 1; i < 8; ++i) pmax = fmaxf(pmax, wmaxA[i]);
    const float rprev = __builtin_amdgcn_logf(pmax);   // log2(max p_{t-1})
    const float inv   = __builtin_amdgcn_rcpf(pmax);
    Racc += (double)rprev;

    // ---- stage q = p/pmax as f16 (in [0,1] -> no overflow) ----
    {
      h2 q0 = __builtin_amdgcn_cvt_pkrtz(pv[0] * inv, pv[1] * inv);
      h2 q1 = __builtin_amdgcn_cvt_pkrtz(pv[2] * inv, pv[3] * inv);
      h2 q2 = __builtin_amdgcn_cvt_pkrtz(pv[4] * inv, pv[5] * inv);
      h2 q3 = __builtin_amdgcn_cvt_pkrtz(pv[6] * inv, pv[7] * inv);
      float4 qq;
      qq.x = __builtin_bit_cast(float, q0);
      qq.y = __builtin_bit_cast(float, q1);
      qq.z = __builtin_bit_cast(float, q2);
      qq.w = __builtin_bit_cast(float, q3);
      *reinterpret_cast<float4*>(PS + 16 * tid) = qq;
    }
    __syncthreads();                       // barrier C: stage ready

    // ---- matvec: a_r = sum_j E[r][j] * q[j]; conflict-free b128 reads ----
    float a0 = 0.f, a1 = 0.f;
    const char* Er0 = dynsm + (2 * wave) * 8192;
    const char* Er1 = Er0 + 8192;
    #pragma unroll
    for (int k = 0; k < 8; ++k) {
      const int off = 1024 * k + 16 * lane;
      const float4 pq = *reinterpret_cast<const float4*>(PS + off);
      const float4 e0 = *reinterpret_cast<const float4*>(Er0 + off);
      const float4 e1 = *reinterpret_cast<const float4*>(Er1 + off);
      const h2 p0 = __builtin_bit_cast(h2, pq.x), p1 = __builtin_bit_cast(h2, pq.y);
      const h2 p2 = __builtin_bit_cast(h2, pq.z), p3 = __builtin_bit_cast(h2, pq.w);
      a0 = FDOT2(__builtin_bit_cast(h2, e0.x), p0, a0);
      a0 = FDOT2(__builtin_bit_cast(h2, e0.y), p1, a0);
      a0 = FDOT2(__builtin_bit_cast(h2, e0.z), p2, a0);
      a0 = FDOT2(__builtin_bit_cast(h2, e0.w), p3, a0);
      a1 = FDOT2(__builtin_bit_cast(h2, e1.x), p0, a1);
      a1 = FDOT2(__builtin_bit_cast(h2, e1.y), p1, a1);
      a1 = FDOT2(__builtin_bit_cast(h2, e1.z), p2, a1);
      a1 = FDOT2(__builtin_bit_cast(h2, e1.w), p3, a1);
    }
    #pragma unroll
    for (int d = 32; d; d >>= 1) {
      a0 += __shfl_xor(a0, d, 64);
      a1 += __shfl_xor(a1, d, 64);
    }

    // y = fe + log2(a') (a' already normalized); publish p_t = 2^y
    if (lane < 2) {
      const float y = (lane == 0) ? (fe0 + __builtin_amdgcn_logf(a0))
                                  : (fe1 + __builtin_amdgcn_logf(a1));
      st_agent(&pring[scur * NTAGS + tagbase + lane], __builtin_amdgcn_exp2f(y));
    }
    __syncthreads();                       // barrier D: vmcnt(0) drains p stores
    if (tid == 0)
      __hip_atomic_store(&flags[scur * 256 + g], 1u,
                         __ATOMIC_RELEASE, __HIP_MEMORY_SCOPE_AGENT);
  }

  // ---- finalization: Z = ln2*(log2(sum p_T) + Racc); out = Z - logprob ----
  if (g == 0 && !giveup) {
    const int sT = T_STEPS & (RING - 1);
    if (wave == 0) {
      unsigned* fl = flags + sT * 256;
      int rounds = 0;
      for (;;) {
        unsigned f0 = __hip_atomic_load(fl + lane,       __ATOMIC_RELAXED, __HIP_MEMORY_SCOPE_AGENT);
        unsigned f1 = __hip_atomic_load(fl + lane + 64,  __ATOMIC_RELAXED, __HIP_MEMORY_SCOPE_AGENT);
        unsigned f2 = __hip_atomic_load(fl + lane + 128, __ATOMIC_RELAXED, __HIP_MEMORY_SCOPE_AGENT);
        unsigned f3 = __hip_atomic_load(fl + lane + 192, __ATOMIC_RELAXED, __HIP_MEMORY_SCOPE_AGENT);
        bool ok = f0 && f1 && f2 && f3;
        if (__ballot(!ok) == 0ull) break;
        if (++rounds > (1 << 17)) break;
        __builtin_amdgcn_s_sleep(1);
      }
      (void)__hip_atomic_load(fl, __ATOMIC_ACQUIRE, __HIP_MEMORY_SCOPE_AGENT);
    }
    __syncthreads();
    const float* pT = pring + sT * NTAGS;
    float s = 0.f;
    #pragma unroll
    for (int i = 0; i < 8; ++i) s += ld_agent(&pT[8 * tid + i]);
    #pragma unroll
    for (int d = 32; d; d >>= 1) s += __shfl_xor(s, d, 64);
    if (lane == 0) wmaxA[wave] = s;
    __syncthreads();
    if (tid == 0) {
      float tot = 0.f;
      #pragma unroll
      for (int i = 0; i < 8; ++i) tot += wmaxA[i];
      const double Z2 = (double)__builtin_amdgcn_logf(tot) + Racc;
      out[0] = (float)(LN2 * Z2 - (double)lp[0]);
    }
  }
}

extern "C" void kernel_launch(void* const* d_in, const int* in_sizes, int n_in,
                              void* d_out, int out_size, void* d_ws, size_t ws_size,
                              hipStream_t stream) {
  const float* feats = (const float*)d_in[0];   // (1024, 1, 4095) f32
  const float* trans = (const float*)d_in[1];   // (4096, 4096) f32
  const int*   tags  = (const int*)d_in[2];     // (1024,) i32
  float* out = (float*)d_out;                   // (1,) f32
  float* ws  = (float*)d_ws;

  (void)hipFuncSetAttribute(reinterpret_cast<const void*>(crf_scan),
                            hipFuncAttributeMaxDynamicSharedMemorySize, 139264);

  crf_init<<<64, 256, 0, stream>>>(ws);
  crf_logprob<<<1, 1024, 0, stream>>>(feats, trans, tags, ws + LP_OFF);
  crf_scan<<<256, 512, 139264, stream>>>(feats, trans, ws, out);
}